// Round 11
// baseline (236.774 us; speedup 1.0000x reference)
//
#include <hip/hip_runtime.h>
#include <hip/hip_bf16.h>

typedef __attribute__((ext_vector_type(8))) short bf16x8;
typedef __attribute__((ext_vector_type(4))) float f32x4;
typedef __attribute__((ext_vector_type(8))) unsigned short ushort8;

#define TOK   4096
#define OUTF  4096
#define INF   4096
#define KE    4160   // 4096 + 16 lora + 48 zero pad -> 130 K-tiles of 32
#define NT    130    // KE / 32
#define RANKD 16

#define VMCNT(n) asm volatile("s_waitcnt vmcnt(" #n ")" ::: "memory")
#define SCHED0   __builtin_amdgcn_sched_barrier(0)
#define BAR      __builtin_amdgcn_s_barrier()

static __device__ __forceinline__ unsigned short f2b(float f) {
  __hip_bfloat16 b = __float2bfloat16(f);
  return __builtin_bit_cast(unsigned short, b);
}

static __device__ __forceinline__ void gload_lds16(const void* g, void* l) {
  __builtin_amdgcn_global_load_lds(
      (const __attribute__((address_space(1))) void*)g,
      (__attribute__((address_space(3))) void*)l, 16, 0, 0);
}

// ---- kernel 1 (prep, 3 concurrent segments):  [r8 verbatim]
__global__ __launch_bounds__(256) void k_prep(const float* __restrict__ x,
                                              const float* __restrict__ A,
                                              const int* __restrict__ q,
                                              const float* __restrict__ absmax,
                                              const float* __restrict__ cb,
                                              const float* __restrict__ B,
                                              unsigned short* __restrict__ Xe,
                                              unsigned short* __restrict__ We) {
  const int lane = threadIdx.x & 63;
  const int wave = threadIdx.x >> 6;
  const int bid  = blockIdx.x;

  if (bid < 256) {
    const int m0 = bid * 16 + wave * 4;
    float p[4][16];
#pragma unroll
    for (int a = 0; a < 4; ++a)
#pragma unroll
      for (int r = 0; r < 16; ++r) p[a][r] = 0.f;

    for (int k = lane; k < INF; k += 64) {
      const float4* a4 = (const float4*)&A[(size_t)k * RANKD];
      float av[16];
      *(float4*)&av[0]  = a4[0];
      *(float4*)&av[4]  = a4[1];
      *(float4*)&av[8]  = a4[2];
      *(float4*)&av[12] = a4[3];
#pragma unroll
      for (int rr = 0; rr < 4; ++rr) {
        const float xv = x[(size_t)(m0 + rr) * INF + k];
#pragma unroll
        for (int r = 0; r < 16; ++r) p[rr][r] = fmaf(xv, av[r], p[rr][r]);
      }
    }
#pragma unroll
    for (int rr = 0; rr < 4; ++rr)
#pragma unroll
      for (int r = 0; r < 16; ++r) {
        float v = p[rr][r];
        v += __shfl_xor(v, 1);
        v += __shfl_xor(v, 2);
        v += __shfl_xor(v, 4);
        v += __shfl_xor(v, 8);
        v += __shfl_xor(v, 16);
        v += __shfl_xor(v, 32);
        p[rr][r] = v;
      }
    const ushort8 z = {0, 0, 0, 0, 0, 0, 0, 0};
#pragma unroll
    for (int rr = 0; rr < 4; ++rr) {
      unsigned short* dst = Xe + (size_t)(m0 + rr) * KE + INF;
      if (lane == 0) {
        ushort8 v0, v1;
#pragma unroll
        for (int r = 0; r < 8; ++r) v0[r] = f2b(2.f * p[rr][r]);
#pragma unroll
        for (int r = 0; r < 8; ++r) v1[r] = f2b(2.f * p[rr][8 + r]);
        *(ushort8*)(dst + 0) = v0;
        *(ushort8*)(dst + 8) = v1;
      }
      if (lane < 6) *(ushort8*)(dst + 16 + lane * 8) = z;   // pad 4112..4159
    }
  } else if (bid < 1280) {
    const int m = (bid - 256) * 4 + wave;
#pragma unroll
    for (int it = 0; it < 8; ++it) {
      const int k0 = it * 512 + lane * 8;
      const float4 v0 = *(const float4*)&x[(size_t)m * INF + k0];
      const float4 v1 = *(const float4*)&x[(size_t)m * INF + k0 + 4];
      ushort8 w;
      w[0] = f2b(v0.x); w[1] = f2b(v0.y); w[2] = f2b(v0.z); w[3] = f2b(v0.w);
      w[4] = f2b(v1.x); w[5] = f2b(v1.y); w[6] = f2b(v1.z); w[7] = f2b(v1.w);
      *(ushort8*)&Xe[(size_t)m * KE + k0] = w;
    }
  } else {
    __shared__ float cbs[16];
    if (threadIdx.x < 16) cbs[threadIdx.x] = cb[threadIdx.x];
    __syncthreads();
    const int o = (bid - 1280) * 4 + wave;
#pragma unroll
    for (int it = 0; it < 8; ++it) {
      const int k0 = it * 512 + lane * 8;
      const int4 q0 = *(const int4*)&q[(size_t)o * INF + k0];
      const int4 q1 = *(const int4*)&q[(size_t)o * INF + k0 + 4];
      const float am = absmax[(size_t)o * 64 + (k0 >> 6)];
      ushort8 w;
      w[0] = f2b(cbs[q0.x] * am); w[1] = f2b(cbs[q0.y] * am);
      w[2] = f2b(cbs[q0.z] * am); w[3] = f2b(cbs[q0.w] * am);
      w[4] = f2b(cbs[q1.x] * am); w[5] = f2b(cbs[q1.y] * am);
      w[6] = f2b(cbs[q1.z] * am); w[7] = f2b(cbs[q1.w] * am);
      *(ushort8*)&We[(size_t)o * KE + k0] = w;
    }
    unsigned short* dst = We + (size_t)o * KE + INF;
    dst[lane] = (lane < 16) ? f2b(B[(size_t)lane * OUTF + o]) : (unsigned short)0;
  }
}

// ---------------- kernel 2: out = Xe @ We^T + bias ----------------
// 128x128 tile, BK=32, 4 waves (2Mx2N, 64x64 out each), ring-4 LDS = 64 KB
// -> 2 independent blocks/CU (cross-block MFMA/LDS overlap). Per K-tile:
// {read 8 frags(T); STAGE(T+2); setprio 16 MFMA; vmcnt(4); bar}.
__global__ __launch_bounds__(256, 2) void k_gemm(const unsigned short* __restrict__ Xe,
                                                 const unsigned short* __restrict__ We,
                                                 const float* __restrict__ bias,
                                                 float* __restrict__ out) {
  extern __shared__ unsigned short LDS[];   // 4 bufs x (A 8KB + B 8KB)/2 = 64 KB
  const char* LB = (const char*)LDS;

  const int tid  = threadIdx.x;
  const int lane = tid & 63;
  const int wave = tid >> 6;        // 0..3
  const int waveM = wave >> 1;      // 0..1 -> rows [waveM*64, +64)
  const int waveN = wave & 1;       // 0..1 -> cols [waveN*64, +64)

  // XCD chunking: 1024 wgs, 128 per XCD as 8 tile-rows x 16 tile-cols (bijective)
  const int wg   = blockIdx.x;
  const int xcd  = wg & 7;
  const int loc  = wg >> 3;                 // 0..127
  const int trB  = ((xcd & 3) * 8 + (loc >> 4)) * 128;
  const int tcB  = ((xcd >> 2) * 16 + (loc & 15)) * 128;

  // ---- staging constants (linear LDS dest, pre-swizzled global source) ----
  // wave stages 32 rows of A and 32 rows of B per tile (4 x gload_lds16)
  const int srow = lane >> 2;
  const int wpr  = ((lane & 3) * 8) ^ (((lane >> 3) & 3) << 3); // ushort offset
  const unsigned short* gA0 = Xe + (size_t)(trB + wave * 32 + srow) * KE + wpr;
  const unsigned short* gA1 = gA0 + (size_t)16 * KE;
  const unsigned short* gB0 = We + (size_t)(tcB + wave * 32 + srow) * KE + wpr;
  const unsigned short* gB1 = gB0 + (size_t)16 * KE;
  const int dA0 = wave * 1024;             // ushort idx within 16KB slot
  const int dA1 = wave * 1024 + 512;
  const int dB0 = 4096 + wave * 1024;
  const int dB1 = 4096 + wave * 1024 + 512;

  // ---- fragment-read constants (swizzled byte offsets; zero-conflict pattern) ----
  const int fr  = lane & 15;
  const int cbk = (lane >> 4) * 16;
  const int sw  = ((fr >> 1) & 3) << 4;
  const int aoff = (waveM * 64 + fr) * 64 + (cbk ^ sw);
  const int boff = 8192 + (waveN * 64 + fr) * 64 + (cbk ^ sw);

  f32x4 acc[4][4];
#pragma unroll
  for (int i = 0; i < 4; ++i)
#pragma unroll
    for (int j = 0; j < 4; ++j) acc[i][j] = f32x4{0.f, 0.f, 0.f, 0.f};

#define STAGE(t)                                                        \
  {                                                                     \
    const int sb_ = ((t) & 3) * 8192;                                   \
    const int k0_ = (t) * 32;                                           \
    gload_lds16(gA0 + k0_, LDS + sb_ + dA0);                            \
    gload_lds16(gA1 + k0_, LDS + sb_ + dA1);                            \
    gload_lds16(gB0 + k0_, LDS + sb_ + dB0);                            \
    gload_lds16(gB1 + k0_, LDS + sb_ + dB1);                            \
  }

  // prologue: stage tiles 0,1; vmcnt(4) -> tile 0 landed
  STAGE(0)
  STAGE(1)
  VMCNT(4);
  BAR; SCHED0;

  bf16x8 a[4], b[4];

  for (int T = 0; T < NT - 2; ++T) {
    const char* base = LB + (T & 3) * 16384;
    // read this tile's 8 fragments
#pragma unroll
    for (int i = 0; i < 4; ++i)
      a[i] = *(const bf16x8*)(base + aoff + i * 1024);
#pragma unroll
    for (int j = 0; j < 4; ++j)
      b[j] = *(const bf16x8*)(base + boff + j * 1024);
    // prefetch tile T+2 into slot (T+2)&3 (its last reader drained at T-2)
    STAGE(T + 2)
    __builtin_amdgcn_s_setprio(1);
#pragma unroll
    for (int i = 0; i < 4; ++i)
#pragma unroll
      for (int j = 0; j < 4; ++j)
        acc[i][j] = __builtin_amdgcn_mfma_f32_16x16x32_bf16(a[i], b[j], acc[i][j], 0, 0, 0);
    __builtin_amdgcn_s_setprio(0);
    VMCNT(4);   // retire tile T+1's 4 loads; T+2's stay in flight
    BAR; SCHED0;
  }

  // peel T = NT-2: no stage; vmcnt(0) so tile NT-1 lands
  {
    const char* base = LB + ((NT - 2) & 3) * 16384;
#pragma unroll
    for (int i = 0; i < 4; ++i)
      a[i] = *(const bf16x8*)(base + aoff + i * 1024);
#pragma unroll
    for (int j = 0; j < 4; ++j)
      b[j] = *(const bf16x8*)(base + boff + j * 1024);
    __builtin_amdgcn_s_setprio(1);
#pragma unroll
    for (int i = 0; i < 4; ++i)
#pragma unroll
      for (int j = 0; j < 4; ++j)
        acc[i][j] = __builtin_amdgcn_mfma_f32_16x16x32_bf16(a[i], b[j], acc[i][j], 0, 0, 0);
    __builtin_amdgcn_s_setprio(0);
    VMCNT(0);
    BAR; SCHED0;
  }
  // peel T = NT-1
  {
    const char* base = LB + ((NT - 1) & 3) * 16384;
#pragma unroll
    for (int i = 0; i < 4; ++i)
      a[i] = *(const bf16x8*)(base + aoff + i * 1024);
#pragma unroll
    for (int j = 0; j < 4; ++j)
      b[j] = *(const bf16x8*)(base + boff + j * 1024);
#pragma unroll
    for (int i = 0; i < 4; ++i)
#pragma unroll
      for (int j = 0; j < 4; ++j)
        acc[i][j] = __builtin_amdgcn_mfma_f32_16x16x32_bf16(a[i], b[j], acc[i][j], 0, 0, 0);
  }
#undef STAGE

  // epilogue: C/D layout col = lane&15, row = (lane>>4)*4 + reg
  const int rq = (lane >> 4) * 4;
#pragma unroll
  for (int j = 0; j < 4; ++j) {
    const int n = tcB + waveN * 64 + j * 16 + fr;
    const float bsv = bias[n];
#pragma unroll
    for (int i = 0; i < 4; ++i) {
      const int m = trB + waveM * 64 + i * 16 + rq;
#pragma unroll
      for (int e = 0; e < 4; ++e)
        out[(size_t)(m + e) * OUTF + n] = acc[i][j][e] + bsv;
    }
  }
}

extern "C" void kernel_launch(void* const* d_in, const int* in_sizes, int n_in,
                              void* d_out, int out_size, void* d_ws, size_t ws_size,
                              hipStream_t stream) {
  const float* x      = (const float*)d_in[0];
  const int*   q      = (const int*)d_in[1];
  const float* absmax = (const float*)d_in[2];
  const float* cb     = (const float*)d_in[3];
  const float* bias   = (const float*)d_in[4];
  const float* A      = (const float*)d_in[5];
  const float* B      = (const float*)d_in[6];
  float* out = (float*)d_out;

  unsigned short* Xe = (unsigned short*)d_ws;              // 4096*4160*2 B
  unsigned short* We = Xe + (size_t)TOK * KE;              // 4096*4160*2 B

  hipFuncSetAttribute((const void*)k_gemm,
                      hipFuncAttributeMaxDynamicSharedMemorySize, 65536);

  k_prep<<<2304, 256, 0, stream>>>(x, A, q, absmax, cb, B, Xe, We);
  k_gemm<<<1024, 256, 65536, stream>>>(Xe, We, bias, out);
}

// Round 12
// 145.102 us; speedup vs baseline: 1.6318x; 1.6318x over previous
//
#include <hip/hip_runtime.h>
#include <hip/hip_bf16.h>

typedef __attribute__((ext_vector_type(4))) int i32x4;

#define TOK   4096
#define OUTF  4096
#define INF   4096
#define KE    4160   // 4096 main + 64 lora block (16 used + 48 zero) -> 65 K-tiles of 64
#define NT    65
#define RANKD 16

#define VMCNT(n) asm volatile("s_waitcnt vmcnt(" #n ")" ::: "memory")
#define SCHED0   __builtin_amdgcn_sched_barrier(0)
#define BAR      __builtin_amdgcn_s_barrier()

static __device__ __forceinline__ void gload_lds16(const void* g, void* l) {
  __builtin_amdgcn_global_load_lds(
      (const __attribute__((address_space(1))) void*)g,
      (__attribute__((address_space(3))) void*)l, 16, 0, 0);
}

static __device__ __forceinline__ unsigned int packq(float a, float b, float c, float d) {
  const int ia = (int)rintf(fminf(fmaxf(a, -127.f), 127.f));
  const int ib = (int)rintf(fminf(fmaxf(b, -127.f), 127.f));
  const int ic = (int)rintf(fminf(fmaxf(c, -127.f), 127.f));
  const int id = (int)rintf(fminf(fmaxf(d, -127.f), 127.f));
  return (ia & 255) | ((ib & 255) << 8) | ((ic & 255) << 16) | ((id & 255) << 24);
}

// ---- kernel 1: blocks 0..255: xA + rowmax -> sx, Xq lora cols + pad.
//      blocks 256..1279: Wq = quantized NF4 dequant (per-row scale wr) + lora B cols (sl).
__global__ __launch_bounds__(256) void k_prep1(const float* __restrict__ x,
                                               const float* __restrict__ A,
                                               const int* __restrict__ q,
                                               const float* __restrict__ absmax,
                                               const float* __restrict__ cb,
                                               const float* __restrict__ B,
                                               signed char* __restrict__ Xq,
                                               signed char* __restrict__ Wq,
                                               float* __restrict__ sx,
                                               float* __restrict__ wr,
                                               float* __restrict__ sl) {
  const int lane = threadIdx.x & 63;
  const int wave = threadIdx.x >> 6;
  const int bid  = blockIdx.x;

  if (bid < 256) {
    const int m0 = bid * 16 + wave * 4;
    float p[4][16], mx[4];
#pragma unroll
    for (int a = 0; a < 4; ++a) {
      mx[a] = 0.f;
#pragma unroll
      for (int r = 0; r < 16; ++r) p[a][r] = 0.f;
    }
    for (int k = lane; k < INF; k += 64) {
      const float4* a4 = (const float4*)&A[(size_t)k * RANKD];
      float av[16];
      *(float4*)&av[0]  = a4[0];
      *(float4*)&av[4]  = a4[1];
      *(float4*)&av[8]  = a4[2];
      *(float4*)&av[12] = a4[3];
#pragma unroll
      for (int rr = 0; rr < 4; ++rr) {
        const float xv = x[(size_t)(m0 + rr) * INF + k];
        mx[rr] = fmaxf(mx[rr], fabsf(xv));
#pragma unroll
        for (int r = 0; r < 16; ++r) p[rr][r] = fmaf(xv, av[r], p[rr][r]);
      }
    }
#pragma unroll
    for (int rr = 0; rr < 4; ++rr) {
#pragma unroll
      for (int r = 0; r < 16; ++r) {
        float v = p[rr][r];
        v += __shfl_xor(v, 1);  v += __shfl_xor(v, 2);
        v += __shfl_xor(v, 4);  v += __shfl_xor(v, 8);
        v += __shfl_xor(v, 16); v += __shfl_xor(v, 32);
        p[rr][r] = v;
      }
      float m = mx[rr];
      m = fmaxf(m, __shfl_xor(m, 1));  m = fmaxf(m, __shfl_xor(m, 2));
      m = fmaxf(m, __shfl_xor(m, 4));  m = fmaxf(m, __shfl_xor(m, 8));
      m = fmaxf(m, __shfl_xor(m, 16)); m = fmaxf(m, __shfl_xor(m, 32));
      mx[rr] = m;
    }
    if (lane == 0) {
#pragma unroll
      for (int rr = 0; rr < 4; ++rr) {
        const float s = fmaxf(mx[rr], 1e-30f) / 127.f;
        sx[m0 + rr] = s;
        const float is4 = 1.f / (4.f * s);     // lora x-side = rint(xA/(4*sx))
        signed char* dst = Xq + (size_t)(m0 + rr) * KE + INF;
        uint4 w;
        w.x = packq(p[rr][0] * is4,  p[rr][1] * is4,  p[rr][2] * is4,  p[rr][3] * is4);
        w.y = packq(p[rr][4] * is4,  p[rr][5] * is4,  p[rr][6] * is4,  p[rr][7] * is4);
        w.z = packq(p[rr][8] * is4,  p[rr][9] * is4,  p[rr][10] * is4, p[rr][11] * is4);
        w.w = packq(p[rr][12] * is4, p[rr][13] * is4, p[rr][14] * is4, p[rr][15] * is4);
        const uint4 z = {0u, 0u, 0u, 0u};
        *(uint4*)(dst + 0)  = w;
        *(uint4*)(dst + 16) = z;
        *(uint4*)(dst + 32) = z;
        *(uint4*)(dst + 48) = z;
      }
    }
  } else {
    __shared__ float cbs[16];
    if (threadIdx.x < 16) cbs[threadIdx.x] = cb[threadIdx.x];
    __syncthreads();
    const int o = (bid - 256) * 4 + wave;
    // am_max over the row's 64 blocks
    float am = absmax[(size_t)o * 64 + lane];
    am = fmaxf(am, __shfl_xor(am, 1));  am = fmaxf(am, __shfl_xor(am, 2));
    am = fmaxf(am, __shfl_xor(am, 4));  am = fmaxf(am, __shfl_xor(am, 8));
    am = fmaxf(am, __shfl_xor(am, 16)); am = fmaxf(am, __shfl_xor(am, 32));
    const float amx = fmaxf(am, 1e-30f);
    const float qs  = 127.f / amx;            // Wq = rint(cb*am * qs)
    if (lane == 0) wr[o] = amx / 127.f;
#pragma unroll
    for (int it = 0; it < 8; ++it) {
      const int k0 = it * 512 + lane * 8;
      const int4 q0 = *(const int4*)&q[(size_t)o * INF + k0];
      const int4 q1 = *(const int4*)&q[(size_t)o * INF + k0 + 4];
      const float f = absmax[(size_t)o * 64 + (k0 >> 6)] * qs;
      uint2 w;
      w.x = packq(cbs[q0.x] * f, cbs[q0.y] * f, cbs[q0.z] * f, cbs[q0.w] * f);
      w.y = packq(cbs[q1.x] * f, cbs[q1.y] * f, cbs[q1.z] * f, cbs[q1.w] * f);
      *(uint2*)&Wq[(size_t)o * KE + k0] = w;
    }
    // lora B cols: per-col scale sB
    const float bv = (lane < 16) ? B[(size_t)lane * OUTF + o] : 0.f;
    float ab = fabsf(bv);
    ab = fmaxf(ab, __shfl_xor(ab, 1)); ab = fmaxf(ab, __shfl_xor(ab, 2));
    ab = fmaxf(ab, __shfl_xor(ab, 4)); ab = fmaxf(ab, __shfl_xor(ab, 8));
    const float sB = fmaxf(ab, 1e-30f) / 127.f;   // valid on lanes 0..15
    if (lane == 0) sl[o] = 8.f * sB;
    signed char* dst = Wq + (size_t)o * KE + INF;
    if (lane < 16) dst[lane] = (signed char)(int)rintf(bv / sB);
    else dst[lane] = 0;
  }
}

// ---- kernel 2: Xq main cols = rint(x / sx[m]) ----
__global__ __launch_bounds__(256) void k_prep2(const float* __restrict__ x,
                                               const float* __restrict__ sx,
                                               signed char* __restrict__ Xq) {
  const int lane = threadIdx.x & 63;
  const int wave = threadIdx.x >> 6;
  const int m = blockIdx.x * 4 + wave;
  const float inv = 1.f / sx[m];
#pragma unroll
  for (int it = 0; it < 8; ++it) {
    const int k0 = it * 512 + lane * 8;
    const float4 v0 = *(const float4*)&x[(size_t)m * INF + k0];
    const float4 v1 = *(const float4*)&x[(size_t)m * INF + k0 + 4];
    uint2 w;
    w.x = packq(v0.x * inv, v0.y * inv, v0.z * inv, v0.w * inv);
    w.y = packq(v1.x * inv, v1.y * inv, v1.z * inv, v1.w * inv);
    *(uint2*)&Xq[(size_t)m * KE + k0] = w;
  }
}

// ---------------- kernel 3: i8 GEMM, out = sx*(wr*main + sl*lora) + bias ----
// 256x256 tile, BK=64 (mfma_i32_16x16x64_i8), 8 waves (2Mx4N), ring-4 LDS
// (4 x 32KB = 128 KB), r8 ledger: {read 12 frags(T); STAGE(T+2); 32 MFMA;
// vmcnt(4); bar}. i32 acc over all 64 main tiles; tile 64 (lora) folded in
// epilogue with its own scale. Zero-conflict XOR swizzle (same geometry as r8).
__global__ __launch_bounds__(512, 2) void k_gemm(const signed char* __restrict__ Xq,
                                                 const signed char* __restrict__ Wq,
                                                 const float* __restrict__ bias,
                                                 const float* __restrict__ sx,
                                                 const float* __restrict__ wr,
                                                 const float* __restrict__ sl,
                                                 float* __restrict__ out) {
  extern __shared__ unsigned char LDS[];   // 4 slots x (A 16KB + B 16KB) = 128 KB
  const char* LB = (const char*)LDS;

  const int tid  = threadIdx.x;
  const int lane = tid & 63;
  const int wave = tid >> 6;        // 0..7
  const int waveM = wave >> 2;      // 0..1 -> rows [waveM*128, +128)
  const int waveN = wave & 3;       // 0..3 -> cols [waveN*64, +64)

  // XCD chunking: 256 wgs, 32 per XCD as 4 tile-rows x 8 tile-cols (bijective)
  const int wg   = blockIdx.x;
  const int xcd  = wg & 7;
  const int loc  = wg >> 3;
  const int trB  = ((xcd & 3) * 4 + (loc >> 3)) * 256;
  const int tcB  = ((xcd >> 2) * 8 + (loc & 7)) * 256;

  // ---- staging (linear LDS dest, pre-swizzled global source); rows = 64 B ----
  const int srow = lane >> 2;                                    // 0..15
  const int wb   = ((lane & 3) * 16) ^ (((lane >> 3) & 3) << 4); // byte in row
  const signed char* gA0 = Xq + (size_t)(trB + wave * 32 + srow) * KE + wb;
  const signed char* gA1 = gA0 + (size_t)16 * KE;
  const signed char* gB0 = Wq + (size_t)(tcB + wave * 32 + srow) * KE + wb;
  const signed char* gB1 = gB0 + (size_t)16 * KE;
  const int dA0 = wave * 2048;            // byte offsets within slot
  const int dA1 = wave * 2048 + 1024;
  const int dB0 = 16384 + wave * 2048;
  const int dB1 = 16384 + wave * 2048 + 1024;

  // ---- fragment reads: row=lane&15, k-quarter=(lane>>4)*16B, XOR swizzle ----
  const int fr   = lane & 15;
  const int kq16 = (lane >> 4) * 16;
  const int sw   = ((fr >> 1) & 3) << 4;
  const int aoff = (waveM * 128 + fr) * 64 + (kq16 ^ sw);
  const int boff = 16384 + (waveN * 64 + fr) * 64 + (kq16 ^ sw);

  i32x4 acc[8][4];
#pragma unroll
  for (int i = 0; i < 8; ++i)
#pragma unroll
    for (int j = 0; j < 4; ++j) acc[i][j] = i32x4{0, 0, 0, 0};

#define STAGE(t)                                                        \
  {                                                                     \
    const int sb_ = ((t) & 3) * 32768;                                  \
    const int k0_ = (t) * 64;                                           \
    gload_lds16(gA0 + k0_, LDS + sb_ + dA0);                            \
    gload_lds16(gA1 + k0_, LDS + sb_ + dA1);                            \
    gload_lds16(gB0 + k0_, LDS + sb_ + dB0);                            \
    gload_lds16(gB1 + k0_, LDS + sb_ + dB1);                            \
  }

  STAGE(0)
  STAGE(1)
  VMCNT(4);
  BAR; SCHED0;

  i32x4 a[8], b[4];

  for (int T = 0; T < NT - 2; ++T) {   // T = 0..62; stages up to tile 64
    const char* base = LB + (T & 3) * 32768;
#pragma unroll
    for (int i = 0; i < 8; ++i)
      a[i] = *(const i32x4*)(base + aoff + i * 1024);
#pragma unroll
    for (int j = 0; j < 4; ++j)
      b[j] = *(const i32x4*)(base + boff + j * 1024);
    STAGE(T + 2)
    __builtin_amdgcn_s_setprio(1);
#pragma unroll
    for (int i = 0; i < 8; ++i)
#pragma unroll
      for (int j = 0; j < 4; ++j)
        acc[i][j] = __builtin_amdgcn_mfma_i32_16x16x64_i8(a[i], b[j], acc[i][j], 0, 0, 0);
    __builtin_amdgcn_s_setprio(0);
    VMCNT(4);   // retire tile T+1's stage; T+2's stays in flight
    BAR; SCHED0;
  }

  // peel T = 63 (slot 3): last main tile; then publish tile 64
  {
    const char* base = LB + 3 * 32768;
#pragma unroll
    for (int i = 0; i < 8; ++i)
      a[i] = *(const i32x4*)(base + aoff + i * 1024);
#pragma unroll
    for (int j = 0; j < 4; ++j)
      b[j] = *(const i32x4*)(base + boff + j * 1024);
    __builtin_amdgcn_s_setprio(1);
#pragma unroll
    for (int i = 0; i < 8; ++i)
#pragma unroll
      for (int j = 0; j < 4; ++j)
        acc[i][j] = __builtin_amdgcn_mfma_i32_16x16x64_i8(a[i], b[j], acc[i][j], 0, 0, 0);
    __builtin_amdgcn_s_setprio(0);
    VMCNT(0);   // tile 64 (lora block, slot 0) landed
    BAR; SCHED0;
  }
#undef STAGE

  // ---- epilogue: lora tile 64 from slot 0 + combined scaling ----
  i32x4 aL[8], bL[4];
#pragma unroll
  for (int i = 0; i < 8; ++i)
    aL[i] = *(const i32x4*)(LB + aoff + i * 1024);
#pragma unroll
  for (int j = 0; j < 4; ++j)
    bL[j] = *(const i32x4*)(LB + boff + j * 1024);

  const int rq = (lane >> 4) * 4;
#pragma unroll
  for (int j = 0; j < 4; ++j) {
    const int n = tcB + waveN * 64 + j * 16 + fr;
    const float wrn = wr[n];
    const float sln = sl[n];
    const float bsn = bias[n];
#pragma unroll
    for (int i = 0; i < 8; ++i) {
      const i32x4 zz = {0, 0, 0, 0};
      const i32x4 t = __builtin_amdgcn_mfma_i32_16x16x64_i8(aL[i], bL[j], zz, 0, 0, 0);
      const int m0v = trB + waveM * 128 + i * 16 + rq;
      const float4 s4 = *(const float4*)&sx[m0v];
      const float* sp = (const float*)&s4;
#pragma unroll
      for (int e = 0; e < 4; ++e) {
        const float v = ((float)acc[i][j][e] * wrn + (float)t[e] * sln) * sp[e] + bsn;
        out[(size_t)(m0v + e) * OUTF + n] = v;
      }
    }
  }
}

extern "C" void kernel_launch(void* const* d_in, const int* in_sizes, int n_in,
                              void* d_out, int out_size, void* d_ws, size_t ws_size,
                              hipStream_t stream) {
  const float* x      = (const float*)d_in[0];
  const int*   q      = (const int*)d_in[1];
  const float* absmax = (const float*)d_in[2];
  const float* cb     = (const float*)d_in[3];
  const float* bias   = (const float*)d_in[4];
  const float* A      = (const float*)d_in[5];
  const float* B      = (const float*)d_in[6];
  float* out = (float*)d_out;

  signed char* Xq = (signed char*)d_ws;                       // 4096*4160 B
  signed char* Wq = Xq + (size_t)TOK * KE;                    // 4096*4160 B
  float* sx = (float*)(Wq + (size_t)OUTF * KE);               // 4096 f32
  float* wr = sx + TOK;                                       // 4096 f32
  float* sl = wr + OUTF;                                      // 4096 f32

  hipFuncSetAttribute((const void*)k_gemm,
                      hipFuncAttributeMaxDynamicSharedMemorySize, 131072);

  k_prep1<<<1280, 256, 0, stream>>>(x, A, q, absmax, cb, B, Xq, Wq, sx, wr, sl);
  k_prep2<<<1024, 256, 0, stream>>>(x, sx, Xq);
  k_gemm<<<256, 512, 131072, stream>>>(Xq, Wq, bias, sx, wr, sl, out);
}